// Round 4
// baseline (403.287 us; speedup 1.0000x reference)
//
#include <hip/hip_runtime.h>
#include <math.h>

// All inputs/outputs fp32 (verified R2).
//
// R4: every matvec restructured as tiled GEMM: block = 64 rows x 8 outputs,
// input tile in LDS (padded, ds_read_b128), weights wave-uniform -> scalar
// cache. Fixes R3's latency-bound per-thread-row weight reads (k_tail 86us,
// VALUBusy 2.5%, occ 5.5%).

__device__ __forceinline__ float block_sum256(float v, float* red) {
    int t = threadIdx.x;
    red[t] = v; __syncthreads();
    for (int st = 128; st > 0; st >>= 1) {
        if (t < st) red[t] += red[t + st];
        __syncthreads();
    }
    float r = red[0]; __syncthreads();
    return r;
}

// ---------------- generic tiled GEMM ----------------
// OUT[r][o] = sum_i IN[r][i] * W[o][i] + B[o]   (W row-major O x K)
// grid = (O/8) * (R/64); block 256. 64 rows x 8 outputs per block.
// MI: 0 = IN direct (stride K); 1 = qkv (q/k: IN+IN2, v: IN; stride 256);
//     2 = pool (mean of 3 consecutive rows of IN, stride 256)
// MO: 0 = none; 1 = relu; 2 = scale outputs o<256 by 32^-0.5
// MW: 0 = single W/B; 1 = split at o=256 (W/B then W2/B2)
template <int K, int MI, int MO, int MW>
__global__ __launch_bounds__(256) void k_gemm(const float* __restrict__ IN,
                                              const float* __restrict__ IN2,
                                              const float* __restrict__ W,
                                              const float* __restrict__ W2,
                                              const float* __restrict__ B,
                                              const float* __restrict__ B2,
                                              float* __restrict__ OUT,
                                              int O, int OG) {
    constexpr int KC = 128;
    constexpr int LDT = KC + 4;  // 132 floats: 528B row stride (16B aligned, bank-staggered)
    __shared__ float tile[64 * LDT];
    int og = blockIdx.x % OG, rg = blockIdx.x / OG;
    int o0 = og * 8, r0 = rg * 64;
    int t = threadIdx.x;
    int r = t & 63;
    int ol = __builtin_amdgcn_readfirstlane(t >> 6);  // wave-uniform -> scalar W loads
    int oa = o0 + ol, ob = o0 + 4 + ol;
    const float *Wa, *Wb;
    float Ba, Bb;
    if (MW == 1) {
        Wa = (oa < 256) ? W + (size_t)oa * K : W2 + (size_t)(oa - 256) * K;
        Wb = (ob < 256) ? W + (size_t)ob * K : W2 + (size_t)(ob - 256) * K;
        Ba = (oa < 256) ? B[oa] : B2[oa - 256];
        Bb = (ob < 256) ? B[ob] : B2[ob - 256];
    } else {
        Wa = W + (size_t)oa * K;
        Wb = W + (size_t)ob * K;
        Ba = B[oa];
        Bb = B[ob];
    }
    float acca = 0.f, accb = 0.f;
    for (int c = 0; c < K / KC; c++) {
        // stage tile: global coalesced (consecutive t -> consecutive col)
        for (int idx = t; idx < 64 * KC; idx += 256) {
            int rr = idx >> 7, ii = idx & (KC - 1);
            int row = r0 + rr, col = c * KC + ii;
            float v;
            if (MI == 0) {
                v = IN[(size_t)row * K + col];
            } else if (MI == 1) {
                float tv = IN[row * 256 + col];
                v = (o0 < 512) ? tv + IN2[row * 256 + col] : tv;
            } else {
                v = (IN[(size_t)(3 * row) * 256 + col] +
                     IN[(size_t)(3 * row + 1) * 256 + col] +
                     IN[(size_t)(3 * row + 2) * 256 + col]) * (1.f / 3.f);
            }
            tile[rr * LDT + ii] = v;
        }
        __syncthreads();
        const float4* wa4 = (const float4*)(Wa + c * KC);
        const float4* wb4 = (const float4*)(Wb + c * KC);
        const float4* trow = (const float4*)(tile + r * LDT);
        #pragma unroll
        for (int i4 = 0; i4 < KC / 4; i4++) {
            float4 x4 = trow[i4];
            float4 a4 = wa4[i4];
            float4 b4 = wb4[i4];
            acca += x4.x * a4.x; acca += x4.y * a4.y;
            acca += x4.z * a4.z; acca += x4.w * a4.w;
            accb += x4.x * b4.x; accb += x4.y * b4.y;
            accb += x4.z * b4.z; accb += x4.w * b4.w;
        }
        __syncthreads();
    }
    acca += Ba; accb += Bb;
    if (MO == 1) { acca = fmaxf(acca, 0.f); accb = fmaxf(accb, 0.f); }
    if (MO == 2) {
        if (oa < 256) acca *= 0.17677669529663687f;
        if (ob < 256) accb *= 0.17677669529663687f;
    }
    OUT[(size_t)(r0 + r) * O + oa] = acca;
    OUT[(size_t)(r0 + r) * O + ob] = accb;
}

// ---------------- attention core ----------------
// grid 128 (per edge), block 256. qkv: (E,768) rows [q(256,scaled)|k|v]. srow: (E,256)
__global__ __launch_bounds__(256) void k_attn(const float* __restrict__ qkv,
                                              float* __restrict__ srow) {
    int e = blockIdx.x, t = threadIdx.x;
    __shared__ float sq[256], sS[1024];
    __shared__ float smax[8], ssum[8];
    sq[t] = qkv[e * 768 + t];
    __syncthreads();
    for (int it = 0; it < 4; it++) {
        int idx = it * 256 + t, h = idx >> 7, f = idx & 127;
        const float* kf = qkv + f * 768 + 256 + h * 32;
        const float* qh = sq + h * 32;
        float s = 0.f;
        for (int d = 0; d < 32; d++) s += qh[d] * kf[d];
        sS[idx] = s;
    }
    __syncthreads();
    if (t < 8) {
        float m = -1e30f;
        for (int f = 0; f < 128; f++) m = fmaxf(m, sS[t * 128 + f]);
        smax[t] = m;
    }
    __syncthreads();
    for (int it = 0; it < 4; it++) {
        int idx = it * 256 + t, h = idx >> 7;
        sS[idx] = __expf(sS[idx] - smax[h]);
    }
    __syncthreads();
    if (t < 8) {
        float s = 0.f;
        for (int f = 0; f < 128; f++) s += sS[t * 128 + f];
        ssum[t] = 1.f / s;
    }
    __syncthreads();
    {
        int h = t >> 5, d = t & 31;
        float acc = 0.f;
        for (int f = 0; f < 128; f++) acc += sS[h * 128 + f] * qkv[f * 768 + 512 + h * 32 + d];
        srow[e * 256 + t] = acc * ssum[h];
    }
}

// ---------------- feat: LN(norm2) + geometry + pos-encode ----------------
// grid 384 (per point), block 256. Writes feat(N,640), x1(E,256; j==0), lxly(N,8), refxy(N,2)
__global__ __launch_bounds__(256) void k_feat(const float* __restrict__ sao,
                                              const float* __restrict__ tgt,
                                              const float* __restrict__ qpos,
                                              const float* __restrict__ n2w,
                                              const float* __restrict__ n2b,
                                              const float* __restrict__ ec,
                                              float* __restrict__ feat,
                                              float* __restrict__ x1,
                                              float* __restrict__ refxy,
                                              int* __restrict__ lxly) {
    int n = blockIdx.x, t = threadIdx.x;
    int e = n / 3, j = n - e * 3;
    __shared__ float red[256];
    // norm2 (recomputed by all 3 blocks of the edge; j==0 publishes x1)
    float acc = sao[e * 256 + t] + tgt[e * 256 + t];
    float mean = block_sum256(acc, red) * (1.f / 256.f);
    float d0 = acc - mean;
    float var = block_sum256(d0 * d0, red) * (1.f / 256.f);
    float xln = d0 * rsqrtf(var + 1e-5f) * n2w[t] + n2b[t];
    if (j == 0) x1[e * 256 + t] = xln;
    float* fg = feat + (size_t)n * 640;
    fg[t] = xln + qpos[e * 256 + t];
    // geometry (redundant scalar work per thread)
    float ax = ec[e * 4 + 0], ay = ec[e * 4 + 1];
    float bx = ec[e * 4 + 2], by = ec[e * 4 + 3];
    float tj = 0.5f * (float)j;
    float dx = bx - ax, dy = by - ay;
    float ptx = __fadd_rn(ax, __fmul_rn(tj, dx));
    float pty = __fadd_rn(ay, __fmul_rn(tj, dy));
    float cxf = floorf(ptx), cyf = floorf(pty);
    int minx = max((int)cxf - 128, 0); if (minx + 256 > 2048) minx = 2048 - 256;
    int miny = max((int)cyf - 128, 0); if (miny + 256 > 2048) miny = 2048 - 256;
    float fminx = (float)minx, fminy = (float)miny;
    float tlx, thx, tly, thy;
    if (dx == 0.f) { tlx = 0.f; thx = 1.f; }
    else { float u1 = (fminx - ax) / dx, u2 = (fminx + 256.f - ax) / dx; tlx = fminf(u1, u2); thx = fmaxf(u1, u2); }
    if (dy == 0.f) { tly = 0.f; thy = 1.f; }
    else { float u1 = (fminy - ay) / dy, u2 = (fminy + 256.f - ay) / dy; tly = fminf(u1, u2); thy = fmaxf(u1, u2); }
    float t0 = fmaxf(fmaxf(tlx, tly), 0.f);
    float t1 = fmaxf(fminf(fminf(thx, thy), 1.f), t0);
    float pxs[3], pys[3];
    pxs[0] = __fadd_rn(ax, __fmul_rn(t0, dx)); pys[0] = __fadd_rn(ay, __fmul_rn(t0, dy));
    pxs[1] = __fadd_rn(ax, __fmul_rn(t1, dx)); pys[1] = __fadd_rn(ay, __fmul_rn(t1, dy));
    pxs[2] = cxf; pys[2] = cyf;
    #pragma unroll
    for (int rep = 0; rep < 2; rep++) {
        int idx = rep * 256 + t;
        if (idx < 384) {
            int jj = idx >> 7, tt = idx & 127, i = tt & 63, kk = i >> 1;
            float invd = __expf(-(float)kk * (9.210340371976184f / 32.f));  // 10000^(-kk/32)
            float vv = (tt < 64) ? pys[jj] : pxs[jj];
            float p = vv * invd;
            fg[256 + idx] = (i & 1) ? __cosf(p) : __sinf(p);
        }
    }
    if (t == 0) {
        refxy[n * 2 + 0] = (cxf - fminx) * (1.f / 256.f);
        refxy[n * 2 + 1] = (cyf - fminy) * (1.f / 256.f);
        lxly[n * 8 + 0] = (int)rintf(fminx * 0.125f);
        lxly[n * 8 + 1] = (int)rintf(fminx * 0.0625f);
        lxly[n * 8 + 2] = (int)rintf(fminx * 0.03125f);
        lxly[n * 8 + 3] = (int)rintf(fminx * 0.015625f);
        lxly[n * 8 + 4] = (int)rintf(fminy * 0.125f);
        lxly[n * 8 + 5] = (int)rintf(fminy * 0.0625f);
        lxly[n * 8 + 6] = (int)rintf(fminy * 0.03125f);
        lxly[n * 8 + 7] = (int)rintf(fminy * 0.015625f);
    }
}

// ---------------- sampling: softmax+loc in-block, linearity-fused ----------------
// grid N*H=3072, block 256. offatr row: [0:256)=off (h*32+l*8+p*2+c), [256:384)=attw (h*16+l*4+p)
__global__ __launch_bounds__(256) void k_sample(const float* __restrict__ offatr,
                                                const float* __restrict__ refxy,
                                                const float* __restrict__ vr,
                                                const int* __restrict__ lxly,
                                                const float* __restrict__ src,
                                                const unsigned char* __restrict__ mask,
                                                const float* __restrict__ valw,
                                                const float* __restrict__ valb,
                                                float* __restrict__ ca) {
    int n = blockIdx.x >> 3, h = blockIdx.x & 7, t = threadIdx.x;
    __shared__ float cw[64];
    __shared__ int cg[64];
    __shared__ float agg[256];
    __shared__ float sl[16], sred[2];
    __shared__ float pagg[32 * 8];
    if (t < 16) sl[t] = offatr[n * 384 + 256 + h * 16 + t];
    __syncthreads();
    if (t == 0) {
        float m = -1e30f;
        for (int i = 0; i < 16; i++) m = fmaxf(m, sl[i]);
        float s = 0.f;
        for (int i = 0; i < 16; i++) s += __expf(sl[i] - m);
        sred[0] = m; sred[1] = 1.f / s;
    }
    __syncthreads();
    if (t < 64) {
        int l = t >> 4, p = (t >> 2) & 3, tap = t & 3;
        int s = 32 >> l;
        int wl = 256 >> l;
        const int img_starts[4] = {0, 65536, 81920, 86016};
        float a = __expf(sl[l * 4 + p] - sred[0]) * sred[1];
        float slv = (float)s;
        float gx = refxy[n * 2 + 0] * vr[l * 2 + 0] + offatr[n * 384 + h * 32 + l * 8 + p * 2 + 0] / slv;
        float gy = refxy[n * 2 + 1] * vr[l * 2 + 1] + offatr[n * 384 + h * 32 + l * 8 + p * 2 + 1] / slv;
        float px = gx * slv - 0.5f, py = gy * slv - 0.5f;
        float x0 = floorf(px), y0 = floorf(py);
        float fx = px - x0, fy = py - y0;
        int xi = (int)x0 + (tap & 1), yi = (int)y0 + (tap >> 1);
        float wt = ((tap & 1) ? fx : (1.f - fx)) * ((tap >> 1) ? fy : (1.f - fy));
        int g = -1;
        if (xi >= 0 && xi < s && yi >= 0 && yi < s) {
            int col = lxly[n * 8 + l] + xi;
            int row = lxly[n * 8 + 4 + l] + yi;
            g = img_starts[l] + row * wl + col;
            if (mask[g]) g = -1;  // masked rows zeroed (incl. bias)
        }
        cw[t] = a * wt;
        cg[t] = g;
    }
    __syncthreads();
    float acc = 0.f, csum = 0.f;
    for (int tp = 0; tp < 64; tp++) {
        int g = cg[tp];
        if (g >= 0) {
            acc += cw[tp] * src[(size_t)g * 256 + t];
            csum += cw[tp];
        }
    }
    agg[t] = acc;
    __syncthreads();
    // value proj: 256 threads = 32 outputs x 8 partial chunks of 32
    {
        int o = t & 31, qtr = t >> 5;
        const float* w = valw + (size_t)(h * 32 + o) * 256 + qtr * 32;
        const float* ag = agg + qtr * 32;
        float p = 0.f;
        for (int i = 0; i < 32; i++) p += ag[i] * w[i];
        pagg[o * 8 + qtr] = p;
    }
    __syncthreads();
    if (t < 32) {
        float o = 0.f;
        for (int qtr = 0; qtr < 8; qtr++) o += pagg[t * 8 + qtr];
        ca[n * 256 + h * 32 + t] = o + csum * valb[h * 32 + t];
    }
}

// ---------------- per-edge LN: out = LN(a + b) ----------------
__global__ __launch_bounds__(256) void k_norm(const float* __restrict__ a,
                                              const float* __restrict__ b,
                                              const float* __restrict__ nw,
                                              const float* __restrict__ nb,
                                              float* __restrict__ out) {
    int e = blockIdx.x, t = threadIdx.x;
    __shared__ float red[256];
    float acc = a[e * 256 + t] + b[e * 256 + t];
    float mean = block_sum256(acc, red) * (1.f / 256.f);
    float d0 = acc - mean;
    float var = block_sum256(d0 * d0, red) * (1.f / 256.f);
    out[e * 256 + t] = d0 * rsqrtf(var + 1e-5f) * nw[t] + nb[t];
}

extern "C" void kernel_launch(void* const* d_in, const int* in_sizes, int n_in,
                              void* d_out, int out_size, void* d_ws, size_t ws_size,
                              hipStream_t stream) {
    (void)in_sizes; (void)n_in; (void)out_size; (void)ws_size;
    const float* tgt  = (const float*)d_in[0];
    const float* qpos = (const float*)d_in[1];
    const float* ec   = (const float*)d_in[2];
    const float* src  = (const float*)d_in[3];
    const unsigned char* mask = (const unsigned char*)d_in[4];
    const float* vr   = (const float*)d_in[5];
    const float* ipw  = (const float*)d_in[6];
    const float* ipb  = (const float*)d_in[7];
    const float* opw  = (const float*)d_in[8];
    const float* opb  = (const float*)d_in[9];
    const float* n1w  = (const float*)d_in[10];
    const float* n1b  = (const float*)d_in[11];
    const float* n2w  = (const float*)d_in[12];
    const float* n2b  = (const float*)d_in[13];
    const float* n3w  = (const float*)d_in[14];
    const float* n3b  = (const float*)d_in[15];
    const float* l0w  = (const float*)d_in[16];
    const float* l0b  = (const float*)d_in[17];
    const float* l1w  = (const float*)d_in[18];
    const float* l1b  = (const float*)d_in[19];
    const float* l2w  = (const float*)d_in[20];
    const float* l2b  = (const float*)d_in[21];
    const float* offw = (const float*)d_in[22];
    const float* offb = (const float*)d_in[23];
    const float* aww  = (const float*)d_in[24];
    const float* awb  = (const float*)d_in[25];
    const float* valw = (const float*)d_in[26];
    const float* valb = (const float*)d_in[27];
    const float* ojw  = (const float*)d_in[28];
    const float* ojb  = (const float*)d_in[29];

    float* ws     = (float*)d_ws;
    float* qkv    = ws;             // 128*768 = 98304
    float* srow   = ws + 98304;     // 32768
    float* sao    = ws + 131072;    // 32768
    float* x1     = ws + 163840;    // 32768
    float* feat   = ws + 196608;    // 384*640 = 245760
    float* nrow   = ws + 442368;    // 98304
    float* offatr = ws + 540672;    // 384*384 = 147456
    float* ca     = ws + 688128;    // 98304
    float* cao    = ws + 786432;    // 32768
    float* x2     = ws + 819200;    // 32768
    float* h1     = ws + 851968;    // 131072
    float* f2     = ws + 983040;    // 32768
    float* refxy  = ws + 1015808;   // 768
    int*   lxly   = (int*)(ws + 1016576); // 3072 ints

    // qkv: O=768 K=256, q/k input tgt+qpos, v input tgt; q scaled
    k_gemm<256, 1, 2, 0><<<96 * 2, 256, 0, stream>>>(tgt, qpos, ipw, nullptr, ipb, nullptr, qkv, 768, 96);
    k_attn<<<128, 256, 0, stream>>>(qkv, srow);
    // out-proj: O=256 K=256
    k_gemm<256, 0, 0, 0><<<32 * 2, 256, 0, stream>>>(srow, nullptr, opw, nullptr, opb, nullptr, sao, 256, 32);
    k_feat<<<384, 256, 0, stream>>>(sao, tgt, qpos, n2w, n2b, ec, feat, x1, refxy, lxly);
    // nq: O=256 K=640
    k_gemm<640, 0, 0, 0><<<32 * 6, 256, 0, stream>>>(feat, nullptr, l0w, nullptr, l0b, nullptr, nrow, 256, 32);
    // off+attw: O=384 K=256, split weights
    k_gemm<256, 0, 0, 1><<<48 * 6, 256, 0, stream>>>(nrow, nullptr, offw, aww, offb, awb, offatr, 384, 48);
    k_sample<<<3072, 256, 0, stream>>>(offatr, refxy, vr, lxly, src, mask, valw, valb, ca);
    // pooled cross-attn out-proj: O=256 K=256, input = mean of 3 ca rows
    k_gemm<256, 2, 0, 0><<<32 * 2, 256, 0, stream>>>(ca, nullptr, ojw, nullptr, ojb, nullptr, cao, 256, 32);
    k_norm<<<128, 256, 0, stream>>>(x1, cao, n1w, n1b, x2);
    // ffn1: O=1024 K=256, relu
    k_gemm<256, 0, 1, 0><<<128 * 2, 256, 0, stream>>>(x2, nullptr, l1w, nullptr, l1b, nullptr, h1, 1024, 128);
    // ffn2: O=256 K=1024
    k_gemm<1024, 0, 0, 0><<<32 * 2, 256, 0, stream>>>(h1, nullptr, l2w, nullptr, l2b, nullptr, f2, 256, 32);
    k_norm<<<128, 256, 0, stream>>>(x2, f2, n3w, n3b, (float*)d_out);
}